// Round 9
// baseline (1223.139 us; speedup 1.0000x reference)
//
#include <hip/hip_runtime.h>

// Matching pursuit via Gram-matrix incremental projection updates.
//   proj0 = X @ D            (fp32 GEMM, bitwise = R2/R5/R6 passing chain)
//   G     = D^T @ D          (fp32 GEMM, triangle + exact mirror)
//   loop 32x: best = argmax|proj|; coef = proj[best]; proj -= coef*G[best,:]
//   recon = sum_i coef_i * DT[a_i, :]
//
// R9: MFMA permanently closed — R3/R4/R7/R8 prove one pick has margin
// < ~1e-6; only the exact R2 fma chain lands on the reference's side.
// Changes vs R6 (passing), all bitwise-identical picks:
//  - k_mp64 scan: pairwise v_max with abs-modifiers (25% fewer scan ops).
//    Tie semantics proven equal to the elementwise strict-> scan.
//  - s_setprio(1) around the update/scan burst (scheduling only).
// Diagnostic: if k_mp64 stays ~600us with VALUBusy dropping, it is
// fetch-bound on the scattered 16KB G-row path (~3.8 TB/s) -> roofline.

#define FD 512
#define NA 4096

#define TM 128
#define TN 128
#define TK 16
#define PADM 132

typedef float f32x4 __attribute__((ext_vector_type(4)));
typedef float f32x2 __attribute__((ext_vector_type(2)));

__device__ __forceinline__ f32x4 ntload4(const float* p) {
  return __builtin_nontemporal_load((const f32x4*)p);
}
__device__ __forceinline__ void ntstore4(float* p, f32x4 v) {
  __builtin_nontemporal_store(v, (f32x4*)p);
}

// ---------- transpose: DT[NA][FD] = D[FD][NA]^T ----------
__global__ __launch_bounds__(1024) void k_transpose(const float* __restrict__ D,
                                                    float* __restrict__ DT) {
  __shared__ float tile[32][33];
  const int bx = blockIdx.x * 32;  // atom block
  const int by = blockIdx.y * 32;  // feature block
  const int tx = threadIdx.x, ty = threadIdx.y;
  tile[ty][tx] = D[(size_t)(by + ty) * NA + bx + tx];
  __syncthreads();
  DT[(size_t)(bx + ty) * FD + by + tx] = tile[tx][ty];
}

// ---------- mirror: fill strictly-lower 128-blocks of G from upper ----------
__global__ __launch_bounds__(1024) void k_mirror(float* __restrict__ G) {
  const int bx = blockIdx.x, by = blockIdx.y;
  if ((bx >> 2) <= (by >> 2)) return;
  __shared__ float tile[32][33];
  const int tx = threadIdx.x, ty = threadIdx.y;
  tile[ty][tx] = G[(size_t)(by * 32 + ty) * NA + bx * 32 + tx];
  __syncthreads();
  G[(size_t)(bx * 32 + ty) * NA + by * 32 + tx] = tile[tx][ty];
}

// ---------- fp32 NN GEMM: C[M][N] = A[M][K] @ B[K][N] (bitwise = R2 chain) ----------
template <bool NT_STORE, bool TRIANGLE>
__global__ __launch_bounds__(256) void k_gemm_nn(const float* __restrict__ A,
                                                 const float* __restrict__ B,
                                                 float* __restrict__ C,
                                                 int M, int N, int K) {
  if (TRIANGLE && (int)blockIdx.x < (int)blockIdx.y) return;
  __shared__ float As[TK][PADM];
  __shared__ float Bs[TK][TN];
  const int t = threadIdx.x;
  const int tx = t & 15, ty = t >> 4;
  const int bm = blockIdx.y * TM, bn = blockIdx.x * TN;
  f32x2 acc2[8][4];
#pragma unroll
  for (int i = 0; i < 8; i++)
#pragma unroll
    for (int j = 0; j < 4; j++) acc2[i][j] = (f32x2){0.f, 0.f};
  for (int kt = 0; kt < K; kt += TK) {
#pragma unroll
    for (int i = 0; i < 2; i++) {
      const int f = t + i * 256;
      const int row = f >> 2;
      const int kc = (f & 3) * 4;
      const float4 v = *(const float4*)(A + (size_t)(bm + row) * K + kt + kc);
      As[kc + 0][row] = v.x;
      As[kc + 1][row] = v.y;
      As[kc + 2][row] = v.z;
      As[kc + 3][row] = v.w;
    }
#pragma unroll
    for (int i = 0; i < 2; i++) {
      const int f = t + i * 256;
      const int kr = f >> 5;
      const int nc = (f & 31) * 4;
      *(float4*)(&Bs[kr][nc]) = *(const float4*)(B + (size_t)(kt + kr) * N + bn + nc);
    }
    __syncthreads();
#pragma unroll
    for (int k = 0; k < TK; k++) {
      float a[8];
      f32x2 b2[4];
      *(float4*)(a) = *(const float4*)(&As[k][ty * 4]);
      *(float4*)(a + 4) = *(const float4*)(&As[k][64 + ty * 4]);
      {
        const f32x2* bp0 = (const f32x2*)(&Bs[k][tx * 4]);
        const f32x2* bp1 = (const f32x2*)(&Bs[k][64 + tx * 4]);
        b2[0] = bp0[0];
        b2[1] = bp0[1];
        b2[2] = bp1[0];
        b2[3] = bp1[1];
      }
#pragma unroll
      for (int i = 0; i < 8; i++) {
        const f32x2 ai = (f32x2){a[i], a[i]};
#pragma unroll
        for (int j = 0; j < 4; j++)
          acc2[i][j] = __builtin_elementwise_fma(ai, b2[j], acc2[i][j]);
      }
    }
    __syncthreads();
  }
#pragma unroll
  for (int ih = 0; ih < 2; ih++)
#pragma unroll
    for (int i = 0; i < 4; i++) {
      float* Crow = C + (size_t)(bm + ih * 64 + ty * 4 + i) * N + bn;
      const f32x4 lo = *(const f32x4*)(&acc2[ih * 4 + i][0]);
      const f32x4 hi = *(const f32x4*)(&acc2[ih * 4 + i][2]);
      if (NT_STORE) {
        ntstore4(Crow + tx * 4, lo);
        ntstore4(Crow + 64 + tx * 4, hi);
      } else {
        *(f32x4*)(Crow + tx * 4) = lo;
        *(f32x4*)(Crow + 64 + tx * 4) = hi;
      }
    }
}

// pairwise argmax step, semantics proven identical to the elementwise
// strict-> ascending scan (incl. all tie cases):
//   m = max(|f0|,|f1|); if (m > av) { ap = (|f0|>=|f1|) ? pay0 : pay1; av = m; }
__device__ __forceinline__ void scan_pair(float f0, float f1, unsigned base,
                                          unsigned sub0, unsigned sub1,
                                          float& av, unsigned& ap) {
  const float a0 = fabsf(f0), a1 = fabsf(f1);
  const float m = fmaxf(a0, a1);
  const unsigned pay0 = base | sub0 | (__float_as_uint(f0) >> 31);
  const unsigned pay1 = base | sub1 | (__float_as_uint(f1) >> 31);
  const unsigned psel = (a0 >= a1) ? pay0 : pay1;
  if (m > av) {
    av = m;
    ap = psel;
  }
}

// ---------- matching pursuit, one wave per sample ----------
// Element map: lane l, reg r = q*4+j  <->  atom idx = q*256 + l*4 + j.
template <bool HAVE_PROJ>
__global__ __launch_bounds__(64, 4) void k_mp64(const float* __restrict__ X,
                                                const float* __restrict__ D,
                                                const float* __restrict__ proj_g,
                                                const float* __restrict__ G,
                                                const float* __restrict__ DT,
                                                float* __restrict__ out,
                                                const int* __restrict__ spars_p) {
  const int s = blockIdx.x;
  const int l = threadIdx.x;
  int sp = spars_p[0];
  if (sp < 0) sp = 0;
  if (sp > 128) sp = 128;

  __shared__ int a_idx_sh[128];
  __shared__ float a_coef_sh[128];
  __shared__ float xsh[FD];

  float p[64];
  if (HAVE_PROJ) {
    const float* pr = proj_g + (size_t)s * NA;
#pragma unroll
    for (int q = 0; q < 16; q++) {
      const f32x4 v = ntload4(pr + (q * 64 + l) * 4);
      p[q * 4 + 0] = v[0];
      p[q * 4 + 1] = v[1];
      p[q * 4 + 2] = v[2];
      p[q * 4 + 3] = v[3];
    }
  } else {
    for (int i = l; i < FD; i += 64) xsh[i] = X[(size_t)s * FD + i];
    __syncthreads();
#pragma unroll
    for (int r = 0; r < 64; r++) p[r] = 0.f;
    for (int k = 0; k < FD; k++) {
      const float xv = xsh[k];
      const float4* Dr = (const float4*)(D + (size_t)k * NA);
#pragma unroll
      for (int q = 0; q < 16; q++) {
        const float4 dv = Dr[q * 64 + l];
        p[q * 4 + 0] = fmaf(xv, dv.x, p[q * 4 + 0]);
        p[q * 4 + 1] = fmaf(xv, dv.y, p[q * 4 + 1]);
        p[q * 4 + 2] = fmaf(xv, dv.z, p[q * 4 + 2]);
        p[q * 4 + 3] = fmaf(xv, dv.w, p[q * 4 + 3]);
      }
    }
  }

  // local argmax accumulators (4-way ILP, group a = q&3; ascending q within
  // a group => strict > keeps first/lowest atom index: jnp.argmax semantics)
  float av[4];
  unsigned ap[4];
#pragma unroll
  for (int a = 0; a < 4; a++) {
    av[a] = -1.f;
    ap[a] = 0xffffffffu;
  }
#pragma unroll
  for (int q = 0; q < 16; q++) {
    const int a = q & 3;
    const unsigned base = (unsigned)(q * 256 + l * 4) << 1;
    scan_pair(p[q * 4 + 0], p[q * 4 + 1], base, 0, 2, av[a], ap[a]);
    scan_pair(p[q * 4 + 2], p[q * 4 + 3], base, 4, 6, av[a], ap[a]);
  }

  for (int it = 0; it < sp; it++) {
    // merge 4 accumulators (tie -> lower payload == lower idx)
    float fa = av[0];
    unsigned pa = ap[0];
#pragma unroll
    for (int a = 1; a < 4; a++) {
      if (av[a] > fa || (av[a] == fa && ap[a] < pa)) {
        fa = av[a];
        pa = ap[a];
      }
    }
    // packed key: abs bits high, ~payload low (max-key => min idx on ties)
    unsigned long long key =
        ((unsigned long long)__float_as_uint(fa) << 32) | (unsigned)(~pa);
#pragma unroll
    for (int off = 1; off < 64; off <<= 1) {
      const unsigned long long ok = __shfl_xor(key, off);
      if (ok > key) key = ok;
    }
    const unsigned pay = ~(unsigned)key;
    const int best = pay >> 1;
    const float ba = __uint_as_float((unsigned)(key >> 32));
    const float coef = (pay & 1) ? -ba : ba;  // == proj[best] exactly

    if (l == 0) {
      a_idx_sh[it] = best;
      a_coef_sh[it] = coef;
    }

    // update p -= coef * G[best,:], fused with next iteration's pair-scan
#pragma unroll
    for (int a = 0; a < 4; a++) {
      av[a] = -1.f;
      ap[a] = 0xffffffffu;
    }
    const float4* Gr = (const float4*)(G + (size_t)best * NA);
#pragma unroll
    for (int h = 0; h < 2; h++) {
      float4 g[8];
#pragma unroll
      for (int q = 0; q < 8; q++) g[q] = Gr[(h * 8 + q) * 64 + l];
      __builtin_amdgcn_s_setprio(1);  // favor this wave through the VALU burst
#pragma unroll
      for (int q = 0; q < 8; q++) {
        const int qq = h * 8 + q;
        const int a = qq & 3;
        const float f0 = fmaf(-coef, g[q].x, p[qq * 4 + 0]);
        const float f1 = fmaf(-coef, g[q].y, p[qq * 4 + 1]);
        const float f2 = fmaf(-coef, g[q].z, p[qq * 4 + 2]);
        const float f3 = fmaf(-coef, g[q].w, p[qq * 4 + 3]);
        p[qq * 4 + 0] = f0;
        p[qq * 4 + 1] = f1;
        p[qq * 4 + 2] = f2;
        p[qq * 4 + 3] = f3;
        const unsigned base = (unsigned)(qq * 256 + l * 4) << 1;
        scan_pair(f0, f1, base, 0, 2, av[a], ap[a]);
        scan_pair(f2, f3, base, 4, 6, av[a], ap[a]);
      }
      __builtin_amdgcn_s_setprio(0);
    }
  }

  __syncthreads();
  // fused recon: out[s,:] = sum_i coef_i * DT[a_i, :]
  float4 acc0 = make_float4(0.f, 0.f, 0.f, 0.f);
  float4 acc1 = make_float4(0.f, 0.f, 0.f, 0.f);
  for (int it = 0; it < sp; it++) {
    const float c = a_coef_sh[it];
    const float4* dr = (const float4*)(DT + (size_t)a_idx_sh[it] * FD);
    const float4 d0 = dr[l];
    const float4 d1 = dr[64 + l];
    acc0.x = fmaf(c, d0.x, acc0.x);
    acc0.y = fmaf(c, d0.y, acc0.y);
    acc0.z = fmaf(c, d0.z, acc0.z);
    acc0.w = fmaf(c, d0.w, acc0.w);
    acc1.x = fmaf(c, d1.x, acc1.x);
    acc1.y = fmaf(c, d1.y, acc1.y);
    acc1.z = fmaf(c, d1.z, acc1.z);
    acc1.w = fmaf(c, d1.w, acc1.w);
  }
  float* orow = out + (size_t)s * FD;
  ntstore4(orow + l * 4, (f32x4){acc0.x, acc0.y, acc0.z, acc0.w});
  ntstore4(orow + 256 + l * 4, (f32x4){acc1.x, acc1.y, acc1.z, acc1.w});
}

extern "C" void kernel_launch(void* const* d_in, const int* in_sizes, int n_in,
                              void* d_out, int out_size, void* d_ws, size_t ws_size,
                              hipStream_t stream) {
  const float* X = (const float*)d_in[0];  // [B][512]
  const float* D = (const float*)d_in[1];  // [512][4096]
  const int* spars = (const int*)d_in[2];  // scalar
  float* out = (float*)d_out;              // [B][512]
  const int B = in_sizes[0] / FD;          // 8192

  char* ws = (char*)d_ws;
  const size_t szDT = (size_t)NA * FD * 4;   // 8 MB
  const size_t szG = (size_t)NA * NA * 4;    // 64 MB
  const size_t szProj = (size_t)B * NA * 4;  // 128 MB

  float* DT = (float*)ws;
  float* G = (float*)(ws + szDT);
  float* proj = (float*)(ws + szDT + szG);
  const size_t need_full = szDT + szG + szProj;  // 200 MB

  k_transpose<<<dim3(NA / 32, FD / 32), dim3(32, 32), 0, stream>>>(D, DT);

  if (ws_size >= need_full) {
    // proj = X @ D (nt store), then G = D^T D triangle + mirror last so G is
    // freshest in cache when k_mp64 starts.
    k_gemm_nn<true, false><<<dim3(NA / TN, B / TM), 256, 0, stream>>>(X, D, proj, B, NA, FD);
    k_gemm_nn<false, true><<<dim3(NA / TN, NA / TM), 256, 0, stream>>>(DT, D, G, NA, NA, FD);
    k_mirror<<<dim3(NA / 32, NA / 32), dim3(32, 32), 0, stream>>>(G);
    k_mp64<true><<<B, 64, 0, stream>>>(X, D, proj, G, DT, out, spars);
  } else {
    k_gemm_nn<false, true><<<dim3(NA / TN, NA / TM), 256, 0, stream>>>(DT, D, G, NA, NA, FD);
    k_mirror<<<dim3(NA / 32, NA / 32), dim3(32, 32), 0, stream>>>(G);
    k_mp64<false><<<B, 64, 0, stream>>>(X, D, nullptr, G, DT, out, spars);
  }
}

// Round 10
// 1204.712 us; speedup vs baseline: 1.0153x; 1.0153x over previous
//
#include <hip/hip_runtime.h>

// Matching pursuit via Gram-matrix incremental projection updates.
//   proj0 = X @ D     (fp32 wide-tile GEMM, bitwise-identical k-chain)
//   G     = D^T @ D   (fp32 128x128 triangle GEMM + exact mirror, = R6)
//   loop 32x: best = argmax|proj|; coef = proj[best]; proj -= coef*G[best,:]
//   recon = sum_i coef_i * DT[a_i, :]
//
// R10: k_mp64 reverted to the exact R6 body (R9's scan-thinning+setprio
// REDUCED delivered BW 3.8->3.5 TB/s: the kernel is overlap-bound; dense
// VALU work covers G-row latency, setprio starved other waves' loads).
// GEMM: old 8x8 micro-tile read 64 LDS B per 64 FLOP = 1 FLOP/B = LDS-read
// ceiling (~78 TF observed). New 8x16 micro-tile (128x256 block tile) reads
// 96 B per 128 FLOP = 1.33 FLOP/B -> bound ~92-105 TF. Retiling preserves
// each output's k-ascending fma chain bit-for-bit (numerics locked: one
// pick in the trajectory has margin < 1e-6; only the R2 chain passes).

#define FD 512
#define NA 4096

#define TM 128
#define TN 128
#define TK 16
#define PADM 132
#define WTN 256  // wide tile N

typedef float f32x4 __attribute__((ext_vector_type(4)));
typedef float f32x2 __attribute__((ext_vector_type(2)));

__device__ __forceinline__ f32x4 ntload4(const float* p) {
  return __builtin_nontemporal_load((const f32x4*)p);
}
__device__ __forceinline__ void ntstore4(float* p, f32x4 v) {
  __builtin_nontemporal_store(v, (f32x4*)p);
}

// ---------- transpose: DT[NA][FD] = D[FD][NA]^T ----------
__global__ __launch_bounds__(1024) void k_transpose(const float* __restrict__ D,
                                                    float* __restrict__ DT) {
  __shared__ float tile[32][33];
  const int bx = blockIdx.x * 32;  // atom block
  const int by = blockIdx.y * 32;  // feature block
  const int tx = threadIdx.x, ty = threadIdx.y;
  tile[ty][tx] = D[(size_t)(by + ty) * NA + bx + tx];
  __syncthreads();
  DT[(size_t)(bx + ty) * FD + by + tx] = tile[tx][ty];
}

// ---------- mirror: fill strictly-lower 128-blocks of G from upper ----------
__global__ __launch_bounds__(1024) void k_mirror(float* __restrict__ G) {
  const int bx = blockIdx.x, by = blockIdx.y;
  if ((bx >> 2) <= (by >> 2)) return;
  __shared__ float tile[32][33];
  const int tx = threadIdx.x, ty = threadIdx.y;
  tile[ty][tx] = G[(size_t)(by * 32 + ty) * NA + bx * 32 + tx];
  __syncthreads();
  G[(size_t)(bx * 32 + ty) * NA + by * 32 + tx] = tile[tx][ty];
}

// ---------- wide fp32 NN GEMM: 128x256 tile, 8x16 per thread ----------
// Per-output k-ascending single-acc fma chain == R2's kernel, bit-for-bit.
__global__ __launch_bounds__(256) void k_gemm_wide(const float* __restrict__ A,
                                                   const float* __restrict__ B,
                                                   float* __restrict__ C,
                                                   int M, int N, int K) {
  __shared__ float As[TK][PADM];  // transposed A tile (128 rows used)
  __shared__ float Bs[TK][WTN];
  const int t = threadIdx.x;
  const int tx = t & 15, ty = t >> 4;
  const int bm = blockIdx.y * TM, bn = blockIdx.x * WTN;

  float acc[8][16];
#pragma unroll
  for (int i = 0; i < 8; i++)
#pragma unroll
    for (int j = 0; j < 16; j++) acc[i][j] = 0.f;

  for (int kt = 0; kt < K; kt += TK) {
// stage A (transposed into LDS), 512 float4
#pragma unroll
    for (int i = 0; i < 2; i++) {
      const int f = t + i * 256;
      const int row = f >> 2;
      const int kc = (f & 3) * 4;
      const float4 v = *(const float4*)(A + (size_t)(bm + row) * K + kt + kc);
      As[kc + 0][row] = v.x;
      As[kc + 1][row] = v.y;
      As[kc + 2][row] = v.z;
      As[kc + 3][row] = v.w;
    }
// stage B (natural layout), 1024 float4
#pragma unroll
    for (int i = 0; i < 4; i++) {
      const int f = t + i * 256;
      const int kr = f >> 6;               // 0..15
      const int nc = (f & 63) * 4;         // 0..252
      *(float4*)(&Bs[kr][nc]) = *(const float4*)(B + (size_t)(kt + kr) * N + bn + nc);
    }
    __syncthreads();
#pragma unroll
    for (int k = 0; k < TK; k++) {
      float a[8], b[16];
      *(float4*)(a) = *(const float4*)(&As[k][ty * 4]);
      *(float4*)(a + 4) = *(const float4*)(&As[k][64 + ty * 4]);
#pragma unroll
      for (int g = 0; g < 4; g++)
        *(float4*)(b + g * 4) = *(const float4*)(&Bs[k][g * 64 + tx * 4]);
#pragma unroll
      for (int i = 0; i < 8; i++)
#pragma unroll
        for (int j = 0; j < 16; j++) acc[i][j] = fmaf(a[i], b[j], acc[i][j]);
    }
    __syncthreads();
  }
#pragma unroll
  for (int ih = 0; ih < 2; ih++)
#pragma unroll
    for (int i = 0; i < 4; i++) {
      float* Crow = C + (size_t)(bm + ih * 64 + ty * 4 + i) * N + bn;
#pragma unroll
      for (int g = 0; g < 4; g++)
        ntstore4(Crow + g * 64 + tx * 4, *(const f32x4*)&acc[ih * 4 + i][g * 4]);
    }
}

// ---------- fp32 NN GEMM 128x128 (G triangle; bitwise = R2 chain) ----------
template <bool NT_STORE, bool TRIANGLE>
__global__ __launch_bounds__(256) void k_gemm_nn(const float* __restrict__ A,
                                                 const float* __restrict__ B,
                                                 float* __restrict__ C,
                                                 int M, int N, int K) {
  if (TRIANGLE && (int)blockIdx.x < (int)blockIdx.y) return;
  __shared__ float As[TK][PADM];
  __shared__ float Bs[TK][TN];
  const int t = threadIdx.x;
  const int tx = t & 15, ty = t >> 4;
  const int bm = blockIdx.y * TM, bn = blockIdx.x * TN;
  f32x2 acc2[8][4];
#pragma unroll
  for (int i = 0; i < 8; i++)
#pragma unroll
    for (int j = 0; j < 4; j++) acc2[i][j] = (f32x2){0.f, 0.f};
  for (int kt = 0; kt < K; kt += TK) {
#pragma unroll
    for (int i = 0; i < 2; i++) {
      const int f = t + i * 256;
      const int row = f >> 2;
      const int kc = (f & 3) * 4;
      const float4 v = *(const float4*)(A + (size_t)(bm + row) * K + kt + kc);
      As[kc + 0][row] = v.x;
      As[kc + 1][row] = v.y;
      As[kc + 2][row] = v.z;
      As[kc + 3][row] = v.w;
    }
#pragma unroll
    for (int i = 0; i < 2; i++) {
      const int f = t + i * 256;
      const int kr = f >> 5;
      const int nc = (f & 31) * 4;
      *(float4*)(&Bs[kr][nc]) = *(const float4*)(B + (size_t)(kt + kr) * N + bn + nc);
    }
    __syncthreads();
#pragma unroll
    for (int k = 0; k < TK; k++) {
      float a[8];
      f32x2 b2[4];
      *(float4*)(a) = *(const float4*)(&As[k][ty * 4]);
      *(float4*)(a + 4) = *(const float4*)(&As[k][64 + ty * 4]);
      {
        const f32x2* bp0 = (const f32x2*)(&Bs[k][tx * 4]);
        const f32x2* bp1 = (const f32x2*)(&Bs[k][64 + tx * 4]);
        b2[0] = bp0[0];
        b2[1] = bp0[1];
        b2[2] = bp1[0];
        b2[3] = bp1[1];
      }
#pragma unroll
      for (int i = 0; i < 8; i++) {
        const f32x2 ai = (f32x2){a[i], a[i]};
#pragma unroll
        for (int j = 0; j < 4; j++)
          acc2[i][j] = __builtin_elementwise_fma(ai, b2[j], acc2[i][j]);
      }
    }
    __syncthreads();
  }
#pragma unroll
  for (int ih = 0; ih < 2; ih++)
#pragma unroll
    for (int i = 0; i < 4; i++) {
      float* Crow = C + (size_t)(bm + ih * 64 + ty * 4 + i) * N + bn;
      const f32x4 lo = *(const f32x4*)(&acc2[ih * 4 + i][0]);
      const f32x4 hi = *(const f32x4*)(&acc2[ih * 4 + i][2]);
      if (NT_STORE) {
        ntstore4(Crow + tx * 4, lo);
        ntstore4(Crow + 64 + tx * 4, hi);
      } else {
        *(f32x4*)(Crow + tx * 4) = lo;
        *(f32x4*)(Crow + 64 + tx * 4) = hi;
      }
    }
}

// ---------- matching pursuit, one wave per sample (EXACT R6 body) ----------
template <bool HAVE_PROJ>
__global__ __launch_bounds__(64, 4) void k_mp64(const float* __restrict__ X,
                                                const float* __restrict__ D,
                                                const float* __restrict__ proj_g,
                                                const float* __restrict__ G,
                                                const float* __restrict__ DT,
                                                float* __restrict__ out,
                                                const int* __restrict__ spars_p) {
  const int s = blockIdx.x;
  const int l = threadIdx.x;
  int sp = spars_p[0];
  if (sp < 0) sp = 0;
  if (sp > 128) sp = 128;

  __shared__ int a_idx_sh[128];
  __shared__ float a_coef_sh[128];
  __shared__ float xsh[FD];

  float p[64];
  if (HAVE_PROJ) {
    const float* pr = proj_g + (size_t)s * NA;
#pragma unroll
    for (int q = 0; q < 16; q++) {
      const f32x4 v = ntload4(pr + (q * 64 + l) * 4);
      p[q * 4 + 0] = v[0];
      p[q * 4 + 1] = v[1];
      p[q * 4 + 2] = v[2];
      p[q * 4 + 3] = v[3];
    }
  } else {
    for (int i = l; i < FD; i += 64) xsh[i] = X[(size_t)s * FD + i];
    __syncthreads();
#pragma unroll
    for (int r = 0; r < 64; r++) p[r] = 0.f;
    for (int k = 0; k < FD; k++) {
      const float xv = xsh[k];
      const float4* Dr = (const float4*)(D + (size_t)k * NA);
#pragma unroll
      for (int q = 0; q < 16; q++) {
        const float4 dv = Dr[q * 64 + l];
        p[q * 4 + 0] = fmaf(xv, dv.x, p[q * 4 + 0]);
        p[q * 4 + 1] = fmaf(xv, dv.y, p[q * 4 + 1]);
        p[q * 4 + 2] = fmaf(xv, dv.z, p[q * 4 + 2]);
        p[q * 4 + 3] = fmaf(xv, dv.w, p[q * 4 + 3]);
      }
    }
  }

  float av[4];
  unsigned ap[4];
#pragma unroll
  for (int a = 0; a < 4; a++) {
    av[a] = -1.f;
    ap[a] = 0xffffffffu;
  }
#pragma unroll
  for (int q = 0; q < 16; q++) {
    const int a = q & 3;
#pragma unroll
    for (int j = 0; j < 4; j++) {
      const float f = p[q * 4 + j];
      const float af = fabsf(f);
      const unsigned pay =
          ((unsigned)(q * 256 + l * 4 + j) << 1) | (__float_as_uint(f) >> 31);
      if (af > av[a]) {
        av[a] = af;
        ap[a] = pay;
      }
    }
  }

  for (int it = 0; it < sp; it++) {
    float fa = av[0];
    unsigned pa = ap[0];
#pragma unroll
    for (int a = 1; a < 4; a++) {
      if (av[a] > fa || (av[a] == fa && ap[a] < pa)) {
        fa = av[a];
        pa = ap[a];
      }
    }
    unsigned long long key =
        ((unsigned long long)__float_as_uint(fa) << 32) | (unsigned)(~pa);
#pragma unroll
    for (int off = 1; off < 64; off <<= 1) {
      const unsigned long long ok = __shfl_xor(key, off);
      if (ok > key) key = ok;
    }
    const unsigned pay = ~(unsigned)key;
    const int best = pay >> 1;
    const float ba = __uint_as_float((unsigned)(key >> 32));
    const float coef = (pay & 1) ? -ba : ba;  // == proj[best] exactly

    if (l == 0) {
      a_idx_sh[it] = best;
      a_coef_sh[it] = coef;
    }

#pragma unroll
    for (int a = 0; a < 4; a++) {
      av[a] = -1.f;
      ap[a] = 0xffffffffu;
    }
    const float4* Gr = (const float4*)(G + (size_t)best * NA);
#pragma unroll
    for (int h = 0; h < 2; h++) {
      float4 g[8];
#pragma unroll
      for (int q = 0; q < 8; q++) g[q] = Gr[(h * 8 + q) * 64 + l];
#pragma unroll
      for (int q = 0; q < 8; q++) {
        const int qq = h * 8 + q;
        const int a = qq & 3;
        float f0 = fmaf(-coef, g[q].x, p[qq * 4 + 0]);
        float f1 = fmaf(-coef, g[q].y, p[qq * 4 + 1]);
        float f2 = fmaf(-coef, g[q].z, p[qq * 4 + 2]);
        float f3 = fmaf(-coef, g[q].w, p[qq * 4 + 3]);
        p[qq * 4 + 0] = f0;
        p[qq * 4 + 1] = f1;
        p[qq * 4 + 2] = f2;
        p[qq * 4 + 3] = f3;
        const unsigned base = (unsigned)(qq * 256 + l * 4) << 1;
        const float a0 = fabsf(f0), a1 = fabsf(f1), a2 = fabsf(f2), a3 = fabsf(f3);
        if (a0 > av[a]) { av[a] = a0; ap[a] = base | 0 | (__float_as_uint(f0) >> 31); }
        if (a1 > av[a]) { av[a] = a1; ap[a] = base | 2 | (__float_as_uint(f1) >> 31); }
        if (a2 > av[a]) { av[a] = a2; ap[a] = base | 4 | (__float_as_uint(f2) >> 31); }
        if (a3 > av[a]) { av[a] = a3; ap[a] = base | 6 | (__float_as_uint(f3) >> 31); }
      }
    }
  }

  __syncthreads();
  float4 acc0 = make_float4(0.f, 0.f, 0.f, 0.f);
  float4 acc1 = make_float4(0.f, 0.f, 0.f, 0.f);
  for (int it = 0; it < sp; it++) {
    const float c = a_coef_sh[it];
    const float4* dr = (const float4*)(DT + (size_t)a_idx_sh[it] * FD);
    const float4 d0 = dr[l];
    const float4 d1 = dr[64 + l];
    acc0.x = fmaf(c, d0.x, acc0.x);
    acc0.y = fmaf(c, d0.y, acc0.y);
    acc0.z = fmaf(c, d0.z, acc0.z);
    acc0.w = fmaf(c, d0.w, acc0.w);
    acc1.x = fmaf(c, d1.x, acc1.x);
    acc1.y = fmaf(c, d1.y, acc1.y);
    acc1.z = fmaf(c, d1.z, acc1.z);
    acc1.w = fmaf(c, d1.w, acc1.w);
  }
  float* orow = out + (size_t)s * FD;
  ntstore4(orow + l * 4, (f32x4){acc0.x, acc0.y, acc0.z, acc0.w});
  ntstore4(orow + 256 + l * 4, (f32x4){acc1.x, acc1.y, acc1.z, acc1.w});
}

extern "C" void kernel_launch(void* const* d_in, const int* in_sizes, int n_in,
                              void* d_out, int out_size, void* d_ws, size_t ws_size,
                              hipStream_t stream) {
  const float* X = (const float*)d_in[0];  // [B][512]
  const float* D = (const float*)d_in[1];  // [512][4096]
  const int* spars = (const int*)d_in[2];  // scalar
  float* out = (float*)d_out;              // [B][512]
  const int B = in_sizes[0] / FD;          // 8192

  char* ws = (char*)d_ws;
  const size_t szDT = (size_t)NA * FD * 4;   // 8 MB
  const size_t szG = (size_t)NA * NA * 4;    // 64 MB
  const size_t szProj = (size_t)B * NA * 4;  // 128 MB

  float* DT = (float*)ws;
  float* G = (float*)(ws + szDT);
  float* proj = (float*)(ws + szDT + szG);
  const size_t need_full = szDT + szG + szProj;  // 200 MB

  k_transpose<<<dim3(NA / 32, FD / 32), dim3(32, 32), 0, stream>>>(D, DT);

  if (ws_size >= need_full) {
    // proj = X @ D with the wide tile (1.33 FLOP/LDS-byte), then G = D^T D
    // triangle + mirror last so G is freshest in cache for k_mp64.
    k_gemm_wide<<<dim3(NA / WTN, B / TM), 256, 0, stream>>>(X, D, proj, B, NA, FD);
    k_gemm_nn<false, true><<<dim3(NA / TN, NA / TM), 256, 0, stream>>>(DT, D, G, NA, NA, FD);
    k_mirror<<<dim3(NA / 32, NA / 32), dim3(32, 32), 0, stream>>>(G);
    k_mp64<true><<<B, 64, 0, stream>>>(X, D, proj, G, DT, out, spars);
  } else {
    k_gemm_nn<false, true><<<dim3(NA / TN, NA / TM), 256, 0, stream>>>(DT, D, G, NA, NA, FD);
    k_mirror<<<dim3(NA / 32, NA / 32), dim3(32, 32), 0, stream>>>(G);
    k_mp64<false><<<B, 64, 0, stream>>>(X, D, nullptr, G, DT, out, spars);
  }
}

// Round 11
// 1171.906 us; speedup vs baseline: 1.0437x; 1.0280x over previous
//
#include <hip/hip_runtime.h>

// Matching pursuit via Gram-matrix incremental projection updates.
//   proj0 = X @ D            (fp32 GEMM, packed v_pk_fma_f32, bitwise = R2)
//   G     = D^T @ D          (fp32 GEMM, upper-triangle 128-blocks + mirror)
//   loop 32x: best = argmax|proj|; coef = proj[best]; proj -= coef*G[best,:]
//   recon = sum_i coef_i * DT[a_i, :]
//
// FINAL (= R6, best passing config at 1174 us). Constraints discovered:
//  - Numerics locked: one pick in the greedy trajectory has margin < 1e-6;
//    only the exact R2 k-ascending fp32 fma chain reproduces the reference
//    (MFMA / fp16 / bf16-limb schemes all flip it: R3/R4/R7/R8).
//  - k_mp64 is fetch-bound on the scattered 16KB G-row path: dur ==
//    FETCH / 3.8 TB/s within 2%. Occupancy/nt/setprio/scan changes all
//    neutral or negative (R1/R5/R9).
//  - fp32 GEMMs at ~88% of the measured 103 TF practical FMA ceiling;
//    pk-FMA and wide-tile retiling both neutral/negative (R6/R10).

#define FD 512
#define NA 4096

#define TM 128
#define TN 128
#define TK 16
#define PADM 132

typedef float f32x4 __attribute__((ext_vector_type(4)));
typedef float f32x2 __attribute__((ext_vector_type(2)));

__device__ __forceinline__ f32x4 ntload4(const float* p) {
  return __builtin_nontemporal_load((const f32x4*)p);
}
__device__ __forceinline__ void ntstore4(float* p, f32x4 v) {
  __builtin_nontemporal_store(v, (f32x4*)p);
}

// ---------- transpose: DT[NA][FD] = D[FD][NA]^T ----------
__global__ __launch_bounds__(1024) void k_transpose(const float* __restrict__ D,
                                                    float* __restrict__ DT) {
  __shared__ float tile[32][33];
  const int bx = blockIdx.x * 32;  // atom block
  const int by = blockIdx.y * 32;  // feature block
  const int tx = threadIdx.x, ty = threadIdx.y;
  tile[ty][tx] = D[(size_t)(by + ty) * NA + bx + tx];
  __syncthreads();
  DT[(size_t)(bx + ty) * FD + by + tx] = tile[tx][ty];
}

// ---------- mirror: fill strictly-lower 128-blocks of G from upper ----------
__global__ __launch_bounds__(1024) void k_mirror(float* __restrict__ G) {
  const int bx = blockIdx.x, by = blockIdx.y;  // target 32-tile
  if ((bx >> 2) <= (by >> 2)) return;          // only strictly-lower 128-blocks
  __shared__ float tile[32][33];
  const int tx = threadIdx.x, ty = threadIdx.y;
  tile[ty][tx] = G[(size_t)(by * 32 + ty) * NA + bx * 32 + tx];
  __syncthreads();
  G[(size_t)(bx * 32 + ty) * NA + by * 32 + tx] = tile[tx][ty];
}

// ---------- fp32 NN GEMM: C[M][N] = A[M][K] @ B[K][N] ----------
// Accumulation order IDENTICAL to R2's passing kernel (k-ascending, one
// accumulator per output). f32x2 packs two INDEPENDENT outputs/instruction.
template <bool NT_STORE, bool TRIANGLE>
__global__ __launch_bounds__(256) void k_gemm_nn(const float* __restrict__ A,
                                                 const float* __restrict__ B,
                                                 float* __restrict__ C,
                                                 int M, int N, int K) {
  if (TRIANGLE && (int)blockIdx.x < (int)blockIdx.y) return;
  __shared__ float As[TK][PADM];
  __shared__ float Bs[TK][TN];
  const int t = threadIdx.x;
  const int tx = t & 15, ty = t >> 4;
  const int bm = blockIdx.y * TM, bn = blockIdx.x * TN;

  f32x2 acc2[8][4];
#pragma unroll
  for (int i = 0; i < 8; i++)
#pragma unroll
    for (int j = 0; j < 4; j++) acc2[i][j] = (f32x2){0.f, 0.f};

  for (int kt = 0; kt < K; kt += TK) {
#pragma unroll
    for (int i = 0; i < 2; i++) {
      const int f = t + i * 256;
      const int row = f >> 2;
      const int kc = (f & 3) * 4;
      const float4 v = *(const float4*)(A + (size_t)(bm + row) * K + kt + kc);
      As[kc + 0][row] = v.x;
      As[kc + 1][row] = v.y;
      As[kc + 2][row] = v.z;
      As[kc + 3][row] = v.w;
    }
#pragma unroll
    for (int i = 0; i < 2; i++) {
      const int f = t + i * 256;
      const int kr = f >> 5;
      const int nc = (f & 31) * 4;
      *(float4*)(&Bs[kr][nc]) = *(const float4*)(B + (size_t)(kt + kr) * N + bn + nc);
    }
    __syncthreads();
#pragma unroll
    for (int k = 0; k < TK; k++) {
      float a[8];
      f32x2 b2[4];
      *(float4*)(a) = *(const float4*)(&As[k][ty * 4]);
      *(float4*)(a + 4) = *(const float4*)(&As[k][64 + ty * 4]);
      {
        const f32x2* bp0 = (const f32x2*)(&Bs[k][tx * 4]);
        const f32x2* bp1 = (const f32x2*)(&Bs[k][64 + tx * 4]);
        b2[0] = bp0[0];
        b2[1] = bp0[1];
        b2[2] = bp1[0];
        b2[3] = bp1[1];
      }
#pragma unroll
      for (int i = 0; i < 8; i++) {
        const f32x2 ai = (f32x2){a[i], a[i]};
#pragma unroll
        for (int j = 0; j < 4; j++)
          acc2[i][j] = __builtin_elementwise_fma(ai, b2[j], acc2[i][j]);
      }
    }
    __syncthreads();
  }
#pragma unroll
  for (int ih = 0; ih < 2; ih++)
#pragma unroll
    for (int i = 0; i < 4; i++) {
      float* Crow = C + (size_t)(bm + ih * 64 + ty * 4 + i) * N + bn;
      const f32x4 lo = *(const f32x4*)(&acc2[ih * 4 + i][0]);
      const f32x4 hi = *(const f32x4*)(&acc2[ih * 4 + i][2]);
      if (NT_STORE) {
        ntstore4(Crow + tx * 4, lo);
        ntstore4(Crow + 64 + tx * 4, hi);
      } else {
        *(f32x4*)(Crow + tx * 4) = lo;
        *(f32x4*)(Crow + 64 + tx * 4) = hi;
      }
    }
}

// ---------- matching pursuit, one wave per sample ----------
// Element map: lane l, reg r = q*4+j  <->  atom idx = q*256 + l*4 + j.
// Argmax via packed-u64 shfl butterfly (abs high, ~((idx<<1)|sign) low):
// every lane gets max|proj|, first-index tie-break AND the sign, so coef
// is recovered with no LDS round trip and no barriers in the loop.
template <bool HAVE_PROJ>
__global__ __launch_bounds__(64, 4) void k_mp64(const float* __restrict__ X,
                                                const float* __restrict__ D,
                                                const float* __restrict__ proj_g,
                                                const float* __restrict__ G,
                                                const float* __restrict__ DT,
                                                float* __restrict__ out,
                                                const int* __restrict__ spars_p) {
  const int s = blockIdx.x;
  const int l = threadIdx.x;
  int sp = spars_p[0];
  if (sp < 0) sp = 0;
  if (sp > 128) sp = 128;

  __shared__ int a_idx_sh[128];
  __shared__ float a_coef_sh[128];
  __shared__ float xsh[FD];

  float p[64];
  if (HAVE_PROJ) {
    const float* pr = proj_g + (size_t)s * NA;
#pragma unroll
    for (int q = 0; q < 16; q++) {
      const f32x4 v = ntload4(pr + (q * 64 + l) * 4);
      p[q * 4 + 0] = v[0];
      p[q * 4 + 1] = v[1];
      p[q * 4 + 2] = v[2];
      p[q * 4 + 3] = v[3];
    }
  } else {
    for (int i = l; i < FD; i += 64) xsh[i] = X[(size_t)s * FD + i];
    __syncthreads();
#pragma unroll
    for (int r = 0; r < 64; r++) p[r] = 0.f;
    for (int k = 0; k < FD; k++) {
      const float xv = xsh[k];
      const float4* Dr = (const float4*)(D + (size_t)k * NA);
#pragma unroll
      for (int q = 0; q < 16; q++) {
        const float4 dv = Dr[q * 64 + l];
        p[q * 4 + 0] = fmaf(xv, dv.x, p[q * 4 + 0]);
        p[q * 4 + 1] = fmaf(xv, dv.y, p[q * 4 + 1]);
        p[q * 4 + 2] = fmaf(xv, dv.z, p[q * 4 + 2]);
        p[q * 4 + 3] = fmaf(xv, dv.w, p[q * 4 + 3]);
      }
    }
  }

  // local argmax accumulators: abs value + payload ((idx<<1)|sign), 4-way ILP.
  // Ascending-idx visit order + strict > keeps the first (lowest) index on
  // ties — jnp.argmax semantics.
  float av[4];
  unsigned ap[4];
#pragma unroll
  for (int a = 0; a < 4; a++) {
    av[a] = -1.f;
    ap[a] = 0xffffffffu;
  }
#pragma unroll
  for (int q = 0; q < 16; q++) {
    const int a = q & 3;
#pragma unroll
    for (int j = 0; j < 4; j++) {
      const float f = p[q * 4 + j];
      const float af = fabsf(f);
      const unsigned pay =
          ((unsigned)(q * 256 + l * 4 + j) << 1) | (__float_as_uint(f) >> 31);
      if (af > av[a]) {
        av[a] = af;
        ap[a] = pay;
      }
    }
  }

  for (int it = 0; it < sp; it++) {
    // merge 4 accumulators (tie -> lower payload == lower idx)
    float fa = av[0];
    unsigned pa = ap[0];
#pragma unroll
    for (int a = 1; a < 4; a++) {
      if (av[a] > fa || (av[a] == fa && ap[a] < pa)) {
        fa = av[a];
        pa = ap[a];
      }
    }
    // packed key: abs bits high (non-negative float -> monotone as uint),
    // ~payload low (so max-key => min idx on abs ties)
    unsigned long long key =
        ((unsigned long long)__float_as_uint(fa) << 32) | (unsigned)(~pa);
#pragma unroll
    for (int off = 1; off < 64; off <<= 1) {
      const unsigned long long ok = __shfl_xor(key, off);
      if (ok > key) key = ok;
    }
    const unsigned pay = ~(unsigned)key;
    const int best = pay >> 1;
    const float ba = __uint_as_float((unsigned)(key >> 32));
    const float coef = (pay & 1) ? -ba : ba;  // == proj[best] exactly

    if (l == 0) {
      a_idx_sh[it] = best;
      a_coef_sh[it] = coef;
    }

    // update p -= coef * G[best,:], fused with next iteration's argmax scan
#pragma unroll
    for (int a = 0; a < 4; a++) {
      av[a] = -1.f;
      ap[a] = 0xffffffffu;
    }
    const float4* Gr = (const float4*)(G + (size_t)best * NA);
#pragma unroll
    for (int h = 0; h < 2; h++) {
      float4 g[8];
#pragma unroll
      for (int q = 0; q < 8; q++) g[q] = Gr[(h * 8 + q) * 64 + l];
#pragma unroll
      for (int q = 0; q < 8; q++) {
        const int qq = h * 8 + q;
        const int a = qq & 3;
        float f0 = fmaf(-coef, g[q].x, p[qq * 4 + 0]);
        float f1 = fmaf(-coef, g[q].y, p[qq * 4 + 1]);
        float f2 = fmaf(-coef, g[q].z, p[qq * 4 + 2]);
        float f3 = fmaf(-coef, g[q].w, p[qq * 4 + 3]);
        p[qq * 4 + 0] = f0;
        p[qq * 4 + 1] = f1;
        p[qq * 4 + 2] = f2;
        p[qq * 4 + 3] = f3;
        const unsigned base = (unsigned)(qq * 256 + l * 4) << 1;
        const float a0 = fabsf(f0), a1 = fabsf(f1), a2 = fabsf(f2), a3 = fabsf(f3);
        if (a0 > av[a]) { av[a] = a0; ap[a] = base | 0 | (__float_as_uint(f0) >> 31); }
        if (a1 > av[a]) { av[a] = a1; ap[a] = base | 2 | (__float_as_uint(f1) >> 31); }
        if (a2 > av[a]) { av[a] = a2; ap[a] = base | 4 | (__float_as_uint(f2) >> 31); }
        if (a3 > av[a]) { av[a] = a3; ap[a] = base | 6 | (__float_as_uint(f3) >> 31); }
      }
    }
  }

  __syncthreads();
  // fused recon: out[s,:] = sum_i coef_i * DT[a_i, :]
  float4 acc0 = make_float4(0.f, 0.f, 0.f, 0.f);
  float4 acc1 = make_float4(0.f, 0.f, 0.f, 0.f);
  for (int it = 0; it < sp; it++) {
    const float c = a_coef_sh[it];
    const float4* dr = (const float4*)(DT + (size_t)a_idx_sh[it] * FD);
    const float4 d0 = dr[l];
    const float4 d1 = dr[64 + l];
    acc0.x = fmaf(c, d0.x, acc0.x);
    acc0.y = fmaf(c, d0.y, acc0.y);
    acc0.z = fmaf(c, d0.z, acc0.z);
    acc0.w = fmaf(c, d0.w, acc0.w);
    acc1.x = fmaf(c, d1.x, acc1.x);
    acc1.y = fmaf(c, d1.y, acc1.y);
    acc1.z = fmaf(c, d1.z, acc1.z);
    acc1.w = fmaf(c, d1.w, acc1.w);
  }
  float* orow = out + (size_t)s * FD;
  ntstore4(orow + l * 4, (f32x4){acc0.x, acc0.y, acc0.z, acc0.w});
  ntstore4(orow + 256 + l * 4, (f32x4){acc1.x, acc1.y, acc1.z, acc1.w});
}

extern "C" void kernel_launch(void* const* d_in, const int* in_sizes, int n_in,
                              void* d_out, int out_size, void* d_ws, size_t ws_size,
                              hipStream_t stream) {
  const float* X = (const float*)d_in[0];  // [B][512]
  const float* D = (const float*)d_in[1];  // [512][4096]
  const int* spars = (const int*)d_in[2];  // scalar
  float* out = (float*)d_out;              // [B][512]
  const int B = in_sizes[0] / FD;          // 8192

  char* ws = (char*)d_ws;
  const size_t szDT = (size_t)NA * FD * 4;   // 8 MB
  const size_t szG = (size_t)NA * NA * 4;    // 64 MB
  const size_t szProj = (size_t)B * NA * 4;  // 128 MB

  float* DT = (float*)ws;
  float* G = (float*)(ws + szDT);
  float* proj = (float*)(ws + szDT + szG);
  const size_t need_full = szDT + szG + szProj;  // 200 MB

  k_transpose<<<dim3(NA / 32, FD / 32), dim3(32, 32), 0, stream>>>(D, DT);

  if (ws_size >= need_full) {
    // proj = X @ D (nt store), then G = D^T D upper-triangle + mirror (so G
    // is freshest in cache when k_mp64 starts).
    k_gemm_nn<true, false><<<dim3(NA / TN, B / TM), 256, 0, stream>>>(X, D, proj, B, NA, FD);
    k_gemm_nn<false, true><<<dim3(NA / TN, NA / TM), 256, 0, stream>>>(DT, D, G, NA, NA, FD);
    k_mirror<<<dim3(NA / 32, NA / 32), dim3(32, 32), 0, stream>>>(G);
    k_mp64<true><<<B, 64, 0, stream>>>(X, D, proj, G, DT, out, spars);
  } else {
    k_gemm_nn<false, true><<<dim3(NA / TN, NA / TM), 256, 0, stream>>>(DT, D, G, NA, NA, FD);
    k_mirror<<<dim3(NA / 32, NA / 32), dim3(32, 32), 0, stream>>>(G);
    k_mp64<false><<<B, 64, 0, stream>>>(X, D, nullptr, G, DT, out, spars);
  }
}